// Round 4
// baseline (806.940 us; speedup 1.0000x reference)
//
#include <hip/hip_runtime.h>

#define SPLITK 256
#define FC1_K 55815

// ---------------- conv1: (128,3,250,250) -> relu -> (128,6,124,124), 5x5 s2 p1
__global__ __launch_bounds__(256) void conv1_k(const float* __restrict__ in,
                                               const float* __restrict__ w,
                                               const float* __restrict__ bias,
                                               float* __restrict__ out) {
    __shared__ float wl[75];
    const int o = blockIdx.y, b = blockIdx.z;
    if (threadIdx.x < 75) wl[threadIdx.x] = w[o * 75 + threadIdx.x];
    __syncthreads();
    int pos = blockIdx.x * 256 + threadIdx.x;
    if (pos >= 124 * 124) return;
    int h = pos / 124, wq = pos % 124;
    float acc = bias[o];
    const float* inb = in + (size_t)b * 3 * 250 * 250;
    #pragma unroll
    for (int c = 0; c < 3; ++c) {
        #pragma unroll
        for (int kh = 0; kh < 5; ++kh) {
            int r = 2 * h - 1 + kh;
            if (r < 0 || r >= 250) continue;
            const float* row = inb + ((size_t)c * 250 + r) * 250;
            #pragma unroll
            for (int kw = 0; kw < 5; ++kw) {
                int cc = 2 * wq - 1 + kw;
                if (cc < 0 || cc >= 250) continue;
                acc = fmaf(row[cc], wl[(c * 5 + kh) * 5 + kw], acc);
            }
        }
    }
    out[(((size_t)b * 6 + o) * 124 + h) * 124 + wq] = fmaxf(acc, 0.0f);
}

// ---------------- conv2: (128,6,123,123) -> relu -> (128,15,62,62), 3x3 s2 p1
__global__ __launch_bounds__(256) void conv2_k(const float* __restrict__ in,
                                               const float* __restrict__ w,
                                               const float* __restrict__ bias,
                                               float* __restrict__ out) {
    __shared__ float wl[54];
    const int o = blockIdx.y, b = blockIdx.z;
    if (threadIdx.x < 54) wl[threadIdx.x] = w[o * 54 + threadIdx.x];
    __syncthreads();
    int pos = blockIdx.x * 256 + threadIdx.x;
    if (pos >= 62 * 62) return;
    int h = pos / 62, wq = pos % 62;
    float acc = bias[o];
    const float* inb = in + (size_t)b * 6 * 123 * 123;
    #pragma unroll
    for (int c = 0; c < 6; ++c) {
        #pragma unroll
        for (int kh = 0; kh < 3; ++kh) {
            int r = 2 * h - 1 + kh;
            if (r < 0 || r >= 123) continue;
            const float* row = inb + ((size_t)c * 123 + r) * 123;
            #pragma unroll
            for (int kw = 0; kw < 3; ++kw) {
                int cc = 2 * wq - 1 + kw;
                if (cc < 0 || cc >= 123) continue;
                acc = fmaf(row[cc], wl[(c * 3 + kh) * 3 + kw], acc);
            }
        }
    }
    out[(((size_t)b * 15 + o) * 62 + h) * 62 + wq] = fmaxf(acc, 0.0f);
}

// ---------------- 2x2 stride-1 maxpool on square images (HI -> HO = HI-1)
__global__ __launch_bounds__(256) void pool_k(const float* __restrict__ in,
                                              float* __restrict__ out,
                                              int HI, int HO, long total) {
    long idx = (long)blockIdx.x * 256 + threadIdx.x;
    if (idx >= total) return;
    int w = (int)(idx % HO);
    long t = idx / HO;
    int h = (int)(t % HO);
    long bc = t / HO;
    const float* p = in + (bc * HI + h) * HI + w;
    out[idx] = fmaxf(fmaxf(p[0], p[1]), fmaxf(p[HI], p[HI + 1]));
}

// ---------------- fc1: split-K GEMM. X(128,K) @ W(120,K)^T -> partials[SPLITK][128][120]
__global__ __launch_bounds__(256) void fc1_k(const float* __restrict__ X,
                                             const float* __restrict__ W,
                                             float* __restrict__ P) {
    __shared__ float Xs[16][132];
    __shared__ float Ws[16][132];
    const int K = FC1_K;
    const int chunk = (K + SPLITK - 1) / SPLITK;  // 219
    int ks = blockIdx.x * chunk;
    int ke = min(ks + chunk, K);
    int tid = threadIdx.x;
    int tx = tid & 15, ty = tid >> 4;
    float acc[8][8];
    #pragma unroll
    for (int i = 0; i < 8; ++i)
        #pragma unroll
        for (int j = 0; j < 8; ++j) acc[i][j] = 0.0f;

    for (int k0 = ks; k0 < ke; k0 += 16) {
        int krem = ke - k0;
        __syncthreads();
        #pragma unroll
        for (int l0 = 0; l0 < 2048; l0 += 256) {
            int l = l0 + tid;
            int kk = l & 15, row = l >> 4;
            int k = k0 + kk;
            bool kv = kk < krem;
            Xs[kk][row] = kv ? X[(size_t)row * K + k] : 0.0f;
            Ws[kk][row] = (kv && row < 120) ? W[(size_t)row * K + k] : 0.0f;
        }
        __syncthreads();
        #pragma unroll
        for (int kk = 0; kk < 16; ++kk) {
            float a[8], bb[8];
            *(float4*)&a[0]  = *(const float4*)&Xs[kk][ty * 8];
            *(float4*)&a[4]  = *(const float4*)&Xs[kk][ty * 8 + 4];
            *(float4*)&bb[0] = *(const float4*)&Ws[kk][tx * 8];
            *(float4*)&bb[4] = *(const float4*)&Ws[kk][tx * 8 + 4];
            #pragma unroll
            for (int i = 0; i < 8; ++i)
                #pragma unroll
                for (int j = 0; j < 8; ++j)
                    acc[i][j] = fmaf(a[i], bb[j], acc[i][j]);
        }
    }
    float* Pp = P + (size_t)blockIdx.x * 15360;
    #pragma unroll
    for (int i = 0; i < 8; ++i) {
        int bI = ty * 8 + i;
        #pragma unroll
        for (int j = 0; j < 8; ++j) {
            int n = tx * 8 + j;
            if (n < 120) Pp[bI * 120 + n] = acc[i][j];
        }
    }
}

// ---------------- tail: reduce partials, fc1 bias+relu, fc2, fc3, quantum head
__global__ __launch_bounds__(128) void tail_k(const float* __restrict__ P,
                                              const float* __restrict__ f1b,
                                              const float* __restrict__ f2w,
                                              const float* __restrict__ f2b,
                                              const float* __restrict__ f3w,
                                              const float* __restrict__ f3b,
                                              const float* __restrict__ qp,
                                              float* __restrict__ out) {
    __shared__ float x1[120];
    __shared__ float x2[84];
    int b = blockIdx.x, tid = threadIdx.x;
    if (tid < 120) {
        float acc = f1b[tid];
        const float* p = P + (size_t)b * 120 + tid;
        for (int s = 0; s < SPLITK; ++s) acc += p[(size_t)s * 15360];
        x1[tid] = fmaxf(acc, 0.0f);
    }
    __syncthreads();
    if (tid < 84) {
        float acc = f2b[tid];
        const float* wr = f2w + tid * 120;
        #pragma unroll 4
        for (int n = 0; n < 120; ++n) acc = fmaf(x1[n], wr[n], acc);
        x2[tid] = fmaxf(acc, 0.0f);
    }
    __syncthreads();
    if (tid == 0) {
        float x = f3b[0];
        for (int m = 0; m < 84; ++m) x = fmaf(x2[m], f3w[m], x);
        // quantum head: 4 qubits, wire w <-> bit (3-w) of state index
        float sr[16], si[16];
        #pragma unroll
        for (int i = 0; i < 16; ++i) { sr[i] = 0.0f; si[i] = 0.0f; }
        sr[0] = 1.0f;
        float c0 = cosf(0.5f * x), s0 = sinf(0.5f * x);
        #pragma unroll
        for (int w = 0; w < 4; ++w) {
            int mask = 8 >> w;
            #pragma unroll
            for (int idx = 0; idx < 16; ++idx) {
                if (idx & mask) continue;
                int i1 = idx | mask;
                float a0r = sr[idx], a0i = si[idx], a1r = sr[i1], a1i = si[i1];
                sr[idx] = c0 * a0r - s0 * a1r;  si[idx] = c0 * a0i - s0 * a1i;
                sr[i1]  = s0 * a0r + c0 * a1r;  si[i1]  = s0 * a0i + c0 * a1i;
            }
        }
        for (int layer = 0; layer < 2; ++layer) {
            #pragma unroll
            for (int w = 0; w < 4; ++w) {
                int gi = (layer * 4 + w) * 3;
                float phi = qp[gi], th = qp[gi + 1], om = qp[gi + 2];
                float hs = 0.5f * (phi + om), hd = 0.5f * (phi - om);
                float ct = cosf(0.5f * th), st = sinf(0.5f * th);
                float chs = cosf(hs), shs = sinf(hs);
                float chd = cosf(hd), shd = sinf(hd);
                float m00r = chs * ct,  m00i = -shs * ct;
                float m01r = -chd * st, m01i = -shd * st;
                float m10r = chd * st,  m10i = -shd * st;
                float m11r = chs * ct,  m11i = shs * ct;
                int mask = 8 >> w;
                #pragma unroll
                for (int idx = 0; idx < 16; ++idx) {
                    if (idx & mask) continue;
                    int i1 = idx | mask;
                    float a0r = sr[idx], a0i = si[idx], a1r = sr[i1], a1i = si[i1];
                    sr[idx] = m00r * a0r - m00i * a0i + m01r * a1r - m01i * a1i;
                    si[idx] = m00r * a0i + m00i * a0r + m01r * a1i + m01i * a1r;
                    sr[i1]  = m10r * a0r - m10i * a0i + m11r * a1r - m11i * a1i;
                    si[i1]  = m10r * a0i + m10i * a0r + m11r * a1i + m11i * a1r;
                }
            }
            #pragma unroll
            for (int cw = 0; cw < 3; ++cw) {
                int cm = 8 >> cw, tm = 8 >> (cw + 1);
                #pragma unroll
                for (int idx = 0; idx < 16; ++idx) {
                    if ((idx & cm) && !(idx & tm)) {
                        int i1 = idx | tm;
                        float tr = sr[idx]; sr[idx] = sr[i1]; sr[i1] = tr;
                        float ti = si[idx]; si[idx] = si[i1]; si[i1] = ti;
                    }
                }
            }
        }
        float q = 0.0f;
        #pragma unroll
        for (int idx = 0; idx < 16; ++idx) {
            float p2 = sr[idx] * sr[idx] + si[idx] * si[idx];
            q += (idx < 8) ? p2 : -p2;
        }
        float pr = 0.5f * (q + 1.0f);
        out[2 * b] = pr;
        out[2 * b + 1] = 1.0f - pr;
    }
}

extern "C" void kernel_launch(void* const* d_in, const int* in_sizes, int n_in,
                              void* d_out, int out_size, void* d_ws, size_t ws_size,
                              hipStream_t stream) {
    const float* inp = (const float*)d_in[0];
    const float* c1w = (const float*)d_in[1];
    const float* c1b = (const float*)d_in[2];
    const float* c2w = (const float*)d_in[3];
    const float* c2b = (const float*)d_in[4];
    const float* f1w = (const float*)d_in[5];
    const float* f1b = (const float*)d_in[6];
    const float* f2w = (const float*)d_in[7];
    const float* f2b = (const float*)d_in[8];
    const float* f3w = (const float*)d_in[9];
    const float* f3b = (const float*)d_in[10];
    const float* qp  = (const float*)d_in[11];
    float* out = (float*)d_out;
    float* ws = (float*)d_ws;

    // ws layout (floats), with reuse:
    //   A (conv1 out)    @ 0         : 128*6*124*124 = 11,809,536
    //   B (pool1 out)    @ 11809536  : 128*6*123*123 = 11,619,072
    //   C (conv2 out)    @ 0         : 128*15*62*62  =  7,380,480  (A dead)
    //   D (pool2 out)    @ 11809536  : 128*15*61*61  =  7,144,320  (B dead)
    //   P (fc1 partials) @ 0         : SPLITK*128*120 = 3,932,160  (C dead)
    float* A = ws;
    float* B = ws + 11809536;
    float* C = ws;
    float* D = ws + 11809536;
    float* P = ws;

    conv1_k<<<dim3(61, 6, 128), 256, 0, stream>>>(inp, c1w, c1b, A);
    long n1 = 128L * 6 * 123 * 123;
    pool_k<<<(n1 + 255) / 256, 256, 0, stream>>>(A, B, 124, 123, n1);
    conv2_k<<<dim3(16, 15, 128), 256, 0, stream>>>(B, c2w, c2b, C);
    long n2 = 128L * 15 * 61 * 61;
    pool_k<<<(n2 + 255) / 256, 256, 0, stream>>>(C, D, 62, 61, n2);
    fc1_k<<<SPLITK, 256, 0, stream>>>(D, f1w, P);
    tail_k<<<128, 128, 0, stream>>>(P, f1b, f2w, f2b, f3w, f3b, qp, out);
}

// Round 5
// 300.627 us; speedup vs baseline: 2.6842x; 2.6842x over previous
//
#include <hip/hip_runtime.h>

#define SPLITK 256
#define FC1_K 55815

// ============ conv1 + relu + pool1 fused ============
// in (128,3,250,250) --5x5 s2 p1--> conv (128,6,124,124) --relu--2x2 s1 pool--> out (128,6,123,123)
// block: 31x31 pooled tile; conv tile 32x32; input tile 3x67x67 in LDS (zero-padded).
__global__ __launch_bounds__(256) void conv1f_k(const float* __restrict__ in,
                                                const float* __restrict__ w,
                                                const float* __restrict__ bias,
                                                float* __restrict__ out) {
    __shared__ float sbuf[3 * 67 * 67];  // 13467 floats; later aliased as conv buf [6][32][33]=6336
    const int tc = blockIdx.x, tr = blockIdx.y, b = blockIdx.z;
    const int pr0 = tr * 31, pc0 = tc * 31;
    const int tid = threadIdx.x;

    // ---- stage input tile (rows 2*pr0-1 .. +66, cols 2*pc0-1 .. +66), zero-pad OOB
    const float* inb = in + (size_t)b * 3 * 250 * 250;
    const int ir0 = 2 * pr0 - 1, ic0 = 2 * pc0 - 1;
    for (int l = tid; l < 3 * 67 * 67; l += 256) {
        int c = l / (67 * 67);
        int rem = l - c * (67 * 67);
        int y = rem / 67;
        int x = rem - y * 67;
        int gr = ir0 + y, gc = ic0 + x;
        float v = 0.0f;
        if (gr >= 0 && gr < 250 && gc >= 0 && gc < 250)
            v = inb[((size_t)c * 250 + gr) * 250 + gc];
        sbuf[l] = v;
    }
    __syncthreads();

    // ---- conv: thread (i,j) computes conv outputs (i,j),(i,j+16),(i+16,j),(i+16,j+16) for 6 ch
    const int i = tid >> 4, j = tid & 15;
    float acc[6][4];
    #pragma unroll
    for (int o = 0; o < 6; ++o) {
        float bv = bias[o];  // uniform -> s_load
        acc[o][0] = bv; acc[o][1] = bv; acc[o][2] = bv; acc[o][3] = bv;
    }
    for (int c = 0; c < 3; ++c) {
        #pragma unroll
        for (int kh = 0; kh < 5; ++kh) {
            const float* r0 = &sbuf[(c * 67 + 2 * i + kh) * 67 + 2 * j];
            const float* r1 = r0 + 32;        // j+16
            const float* r2 = r0 + 32 * 67;   // i+16
            const float* r3 = r2 + 32;
            float A[5], B[5], C[5], D[5];
            #pragma unroll
            for (int t = 0; t < 5; ++t) { A[t] = r0[t]; B[t] = r1[t]; C[t] = r2[t]; D[t] = r3[t]; }
            #pragma unroll
            for (int kw = 0; kw < 5; ++kw) {
                #pragma unroll
                for (int o = 0; o < 6; ++o) {
                    float wv = w[o * 75 + c * 25 + kh * 5 + kw];  // uniform -> s_load
                    acc[o][0] = fmaf(A[kw], wv, acc[o][0]);
                    acc[o][1] = fmaf(B[kw], wv, acc[o][1]);
                    acc[o][2] = fmaf(C[kw], wv, acc[o][2]);
                    acc[o][3] = fmaf(D[kw], wv, acc[o][3]);
                }
            }
        }
    }
    __syncthreads();  // all input reads done -> safe to alias

    // ---- relu + stash conv tile in LDS [6][32][33]
    float* cv = sbuf;
    #pragma unroll
    for (int o = 0; o < 6; ++o) {
        cv[(o * 32 + i) * 33 + j]            = fmaxf(acc[o][0], 0.0f);
        cv[(o * 32 + i) * 33 + (j + 16)]     = fmaxf(acc[o][1], 0.0f);
        cv[(o * 32 + i + 16) * 33 + j]       = fmaxf(acc[o][2], 0.0f);
        cv[(o * 32 + i + 16) * 33 + (j + 16)] = fmaxf(acc[o][3], 0.0f);
    }
    __syncthreads();

    // ---- pool 2x2 s1 -> 31x31 valid outputs, write global
    for (int l = tid; l < 6 * 31 * 31; l += 256) {
        int o = l / 961;
        int rem = l - o * 961;
        int pi = rem / 31;
        int pj = rem - pi * 31;
        int gr = pr0 + pi, gc = pc0 + pj;
        if (gr < 123 && gc < 123) {
            const float* p = &cv[(o * 32 + pi) * 33 + pj];
            float m = fmaxf(fmaxf(p[0], p[1]), fmaxf(p[33], p[34]));
            out[((size_t)(b * 6 + o) * 123 + gr) * 123 + gc] = m;
        }
    }
}

// ============ conv2 + relu + pool2 fused ============
// in (128,6,123,123) --3x3 s2 p1--> conv (128,15,62,62) --relu--pool--> out (128,15,61,61)
// block: 15x15 pooled tile; conv tile 16x16 (1 thread each, 15 ch in regs); input 6x33x33 LDS.
__global__ __launch_bounds__(256) void conv2f_k(const float* __restrict__ in,
                                                const float* __restrict__ w,
                                                const float* __restrict__ bias,
                                                float* __restrict__ out) {
    __shared__ float sbuf[6 * 33 * 33];  // 6534 floats; aliased as conv buf [15][16][17]=4080
    const int tc = blockIdx.x, tr = blockIdx.y, b = blockIdx.z;
    const int pr0 = tr * 15, pc0 = tc * 15;
    const int tid = threadIdx.x;

    const float* inb = in + (size_t)b * 6 * 123 * 123;
    const int ir0 = 2 * pr0 - 1, ic0 = 2 * pc0 - 1;
    for (int l = tid; l < 6 * 33 * 33; l += 256) {
        int c = l / (33 * 33);
        int rem = l - c * (33 * 33);
        int y = rem / 33;
        int x = rem - y * 33;
        int gr = ir0 + y, gc = ic0 + x;
        float v = 0.0f;
        if (gr >= 0 && gr < 123 && gc >= 0 && gc < 123)
            v = inb[((size_t)c * 123 + gr) * 123 + gc];
        sbuf[l] = v;
    }
    __syncthreads();

    const int ti = tid >> 4, tj = tid & 15;
    float acc[15];
    #pragma unroll
    for (int o = 0; o < 15; ++o) acc[o] = bias[o];
    for (int c = 0; c < 6; ++c) {
        #pragma unroll
        for (int kh = 0; kh < 3; ++kh) {
            const float* r = &sbuf[(c * 33 + 2 * ti + kh) * 33 + 2 * tj];
            float a0 = r[0], a1 = r[1], a2 = r[2];
            #pragma unroll
            for (int o = 0; o < 15; ++o) {
                const float* wr = &w[o * 54 + c * 9 + kh * 3];  // uniform -> s_load
                acc[o] = fmaf(a0, wr[0], acc[o]);
                acc[o] = fmaf(a1, wr[1], acc[o]);
                acc[o] = fmaf(a2, wr[2], acc[o]);
            }
        }
    }
    __syncthreads();

    float* cv = sbuf;  // [15][16][17]
    #pragma unroll
    for (int o = 0; o < 15; ++o)
        cv[(o * 16 + ti) * 17 + tj] = fmaxf(acc[o], 0.0f);
    __syncthreads();

    for (int l = tid; l < 15 * 15 * 15; l += 256) {
        int o = l / 225;
        int rem = l - o * 225;
        int pi = rem / 15;
        int pj = rem - pi * 15;
        int gr = pr0 + pi, gc = pc0 + pj;
        if (gr < 61 && gc < 61) {
            const float* p = &cv[(o * 16 + pi) * 17 + pj];
            float m = fmaxf(fmaxf(p[0], p[1]), fmaxf(p[17], p[18]));
            out[((size_t)(b * 15 + o) * 61 + gr) * 61 + gc] = m;
        }
    }
}

// ---------------- fc1: split-K GEMM. X(128,K) @ W(120,K)^T -> partials[SPLITK][128][120]
__global__ __launch_bounds__(256) void fc1_k(const float* __restrict__ X,
                                             const float* __restrict__ W,
                                             float* __restrict__ P) {
    __shared__ float Xs[16][132];
    __shared__ float Ws[16][132];
    const int K = FC1_K;
    const int chunk = (K + SPLITK - 1) / SPLITK;  // 219
    int ks = blockIdx.x * chunk;
    int ke = min(ks + chunk, K);
    int tid = threadIdx.x;
    int tx = tid & 15, ty = tid >> 4;
    float acc[8][8];
    #pragma unroll
    for (int i = 0; i < 8; ++i)
        #pragma unroll
        for (int j = 0; j < 8; ++j) acc[i][j] = 0.0f;

    for (int k0 = ks; k0 < ke; k0 += 16) {
        int krem = ke - k0;
        __syncthreads();
        #pragma unroll
        for (int l0 = 0; l0 < 2048; l0 += 256) {
            int l = l0 + tid;
            int kk = l & 15, row = l >> 4;
            int k = k0 + kk;
            bool kv = kk < krem;
            Xs[kk][row] = kv ? X[(size_t)row * K + k] : 0.0f;
            Ws[kk][row] = (kv && row < 120) ? W[(size_t)row * K + k] : 0.0f;
        }
        __syncthreads();
        #pragma unroll
        for (int kk = 0; kk < 16; ++kk) {
            float a[8], bb[8];
            *(float4*)&a[0]  = *(const float4*)&Xs[kk][ty * 8];
            *(float4*)&a[4]  = *(const float4*)&Xs[kk][ty * 8 + 4];
            *(float4*)&bb[0] = *(const float4*)&Ws[kk][tx * 8];
            *(float4*)&bb[4] = *(const float4*)&Ws[kk][tx * 8 + 4];
            #pragma unroll
            for (int i = 0; i < 8; ++i)
                #pragma unroll
                for (int j = 0; j < 8; ++j)
                    acc[i][j] = fmaf(a[i], bb[j], acc[i][j]);
        }
    }
    float* Pp = P + (size_t)blockIdx.x * 15360;
    #pragma unroll
    for (int i = 0; i < 8; ++i) {
        int bI = ty * 8 + i;
        #pragma unroll
        for (int j = 0; j < 8; ++j) {
            int n = tx * 8 + j;
            if (n < 120) Pp[bI * 120 + n] = acc[i][j];
        }
    }
}

// ---------------- tail: reduce partials, fc1 bias+relu, fc2, fc3, quantum head
__global__ __launch_bounds__(128) void tail_k(const float* __restrict__ P,
                                              const float* __restrict__ f1b,
                                              const float* __restrict__ f2w,
                                              const float* __restrict__ f2b,
                                              const float* __restrict__ f3w,
                                              const float* __restrict__ f3b,
                                              const float* __restrict__ qp,
                                              float* __restrict__ out) {
    __shared__ float x1[120];
    __shared__ float x2[84];
    int b = blockIdx.x, tid = threadIdx.x;
    if (tid < 120) {
        float acc = f1b[tid];
        const float* p = P + (size_t)b * 120 + tid;
        for (int s = 0; s < SPLITK; ++s) acc += p[(size_t)s * 15360];
        x1[tid] = fmaxf(acc, 0.0f);
    }
    __syncthreads();
    if (tid < 84) {
        float acc = f2b[tid];
        const float* wr = f2w + tid * 120;
        #pragma unroll 4
        for (int n = 0; n < 120; ++n) acc = fmaf(x1[n], wr[n], acc);
        x2[tid] = fmaxf(acc, 0.0f);
    }
    __syncthreads();
    if (tid == 0) {
        float x = f3b[0];
        for (int m = 0; m < 84; ++m) x = fmaf(x2[m], f3w[m], x);
        float sr[16], si[16];
        #pragma unroll
        for (int i = 0; i < 16; ++i) { sr[i] = 0.0f; si[i] = 0.0f; }
        sr[0] = 1.0f;
        float c0 = cosf(0.5f * x), s0 = sinf(0.5f * x);
        #pragma unroll
        for (int w = 0; w < 4; ++w) {
            int mask = 8 >> w;
            #pragma unroll
            for (int idx = 0; idx < 16; ++idx) {
                if (idx & mask) continue;
                int i1 = idx | mask;
                float a0r = sr[idx], a0i = si[idx], a1r = sr[i1], a1i = si[i1];
                sr[idx] = c0 * a0r - s0 * a1r;  si[idx] = c0 * a0i - s0 * a1i;
                sr[i1]  = s0 * a0r + c0 * a1r;  si[i1]  = s0 * a0i + c0 * a1i;
            }
        }
        for (int layer = 0; layer < 2; ++layer) {
            #pragma unroll
            for (int w = 0; w < 4; ++w) {
                int gi = (layer * 4 + w) * 3;
                float phi = qp[gi], th = qp[gi + 1], om = qp[gi + 2];
                float hs = 0.5f * (phi + om), hd = 0.5f * (phi - om);
                float ct = cosf(0.5f * th), st = sinf(0.5f * th);
                float chs = cosf(hs), shs = sinf(hs);
                float chd = cosf(hd), shd = sinf(hd);
                float m00r = chs * ct,  m00i = -shs * ct;
                float m01r = -chd * st, m01i = -shd * st;
                float m10r = chd * st,  m10i = -shd * st;
                float m11r = chs * ct,  m11i = shs * ct;
                int mask = 8 >> w;
                #pragma unroll
                for (int idx = 0; idx < 16; ++idx) {
                    if (idx & mask) continue;
                    int i1 = idx | mask;
                    float a0r = sr[idx], a0i = si[idx], a1r = sr[i1], a1i = si[i1];
                    sr[idx] = m00r * a0r - m00i * a0i + m01r * a1r - m01i * a1i;
                    si[idx] = m00r * a0i + m00i * a0r + m01r * a1i + m01i * a1r;
                    sr[i1]  = m10r * a0r - m10i * a0i + m11r * a1r - m11i * a1i;
                    si[i1]  = m10r * a0i + m10i * a0r + m11r * a1i + m11i * a1r;
                }
            }
            #pragma unroll
            for (int cw = 0; cw < 3; ++cw) {
                int cm = 8 >> cw, tm = 8 >> (cw + 1);
                #pragma unroll
                for (int idx = 0; idx < 16; ++idx) {
                    if ((idx & cm) && !(idx & tm)) {
                        int i1 = idx | tm;
                        float tr = sr[idx]; sr[idx] = sr[i1]; sr[i1] = tr;
                        float ti = si[idx]; si[idx] = si[i1]; si[i1] = ti;
                    }
                }
            }
        }
        float q = 0.0f;
        #pragma unroll
        for (int idx = 0; idx < 16; ++idx) {
            float p2 = sr[idx] * sr[idx] + si[idx] * si[idx];
            q += (idx < 8) ? p2 : -p2;
        }
        float pr = 0.5f * (q + 1.0f);
        out[2 * b] = pr;
        out[2 * b + 1] = 1.0f - pr;
    }
}

extern "C" void kernel_launch(void* const* d_in, const int* in_sizes, int n_in,
                              void* d_out, int out_size, void* d_ws, size_t ws_size,
                              hipStream_t stream) {
    const float* inp = (const float*)d_in[0];
    const float* c1w = (const float*)d_in[1];
    const float* c1b = (const float*)d_in[2];
    const float* c2w = (const float*)d_in[3];
    const float* c2b = (const float*)d_in[4];
    const float* f1w = (const float*)d_in[5];
    const float* f1b = (const float*)d_in[6];
    const float* f2w = (const float*)d_in[7];
    const float* f2b = (const float*)d_in[8];
    const float* f3w = (const float*)d_in[9];
    const float* f3b = (const float*)d_in[10];
    const float* qp  = (const float*)d_in[11];
    float* out = (float*)d_out;
    float* ws = (float*)d_ws;

    // ws layout (floats):
    //   B (pool1 out) @ 0          : 128*6*123*123  = 11,619,072
    //   D (pool2 out) @ 11,619,072 : 128*15*61*61   =  7,144,320
    //   P (fc1 part.) @ 18,763,392 : SPLITK*128*120 =  3,932,160   (total 90.8 MB)
    float* B = ws;
    float* D = ws + 11619072;
    float* P = ws + 18763392;

    conv1f_k<<<dim3(4, 4, 128), 256, 0, stream>>>(inp, c1w, c1b, B);
    conv2f_k<<<dim3(5, 5, 128), 256, 0, stream>>>(B, c2w, c2b, D);
    fc1_k<<<SPLITK, 256, 0, stream>>>(D, f1w, P);
    tail_k<<<128, 128, 0, stream>>>(P, f1b, f2w, f2b, f3w, f3b, qp, out);
}

// Round 6
// 214.234 us; speedup vs baseline: 3.7666x; 1.4033x over previous
//
#include <hip/hip_runtime.h>

#define SPLITK 256
#define FC1_K 55815

// ============ conv1 + relu + pool1 fused (v2) ============
// in (128,3,250,250) --5x5 s2 p1--> conv (128,6,124,124) --relu--2x2 s1 pool--> out (128,6,123,123)
// Block: 31x31 pooled tile (conv 32x32). Per-channel staging: 67x67 tile, stride-68 pad.
// Thread (i,j) of 16x16 computes conv quad (2i+di, 2j+dj), all 6 out-channels.
__global__ __launch_bounds__(256) void conv1f_k(const float* __restrict__ in,
                                                const float* __restrict__ w,
                                                const float* __restrict__ bias,
                                                float* __restrict__ out) {
    __shared__ float sbuf[6336];  // stage: 67*68=4556 used; stash alias: [6][32][33]=6336
    const int tc = blockIdx.x, tr = blockIdx.y, b = blockIdx.z;
    const int pr0 = tr * 31, pc0 = tc * 31;
    const int tid = threadIdx.x;
    const int i = tid >> 4, j = tid & 15;
    const float* inb = in + (size_t)b * 3 * 250 * 250;
    const int ir0 = 2 * pr0 - 1, ic0 = 2 * pc0 - 1;

    float acc[6][2][2];
    #pragma unroll
    for (int o = 0; o < 6; ++o) {
        float bv = bias[o];
        acc[o][0][0] = bv; acc[o][0][1] = bv; acc[o][1][0] = bv; acc[o][1][1] = bv;
    }

    for (int c = 0; c < 3; ++c) {
        __syncthreads();  // protect previous channel's reads
        // stage channel c (67x67 -> stride 68)
        for (int l = tid; l < 4489; l += 256) {
            int y = l / 67, x = l - y * 67;
            int gr = ir0 + y, gc = ic0 + x;
            float v = 0.0f;
            if (gr >= 0 && gr < 250 && gc >= 0 && gc < 250)
                v = inb[((size_t)c * 250 + gr) * 250 + gc];
            sbuf[y * 68 + x] = v;
        }
        __syncthreads();

        #pragma unroll
        for (int wr = 0; wr < 7; ++wr) {
            // input window row 4i+wr, cols 4j..4j+6 (aligned: (4i+wr)*68+4j % 4 == 0)
            const float* rp = &sbuf[(4 * i + wr) * 68 + 4 * j];
            float row[7];
            float4 v4 = *(const float4*)rp;
            float2 v2 = *(const float2*)(rp + 4);
            row[0] = v4.x; row[1] = v4.y; row[2] = v4.z; row[3] = v4.w;
            row[4] = v2.x; row[5] = v2.y; row[6] = rp[6];
            #pragma unroll
            for (int o = 0; o < 6; ++o) {
                #pragma unroll
                for (int kw = 0; kw < 5; ++kw) {
                    if (wr <= 4) {  // di=0, kh=wr
                        float wv = w[o * 75 + c * 25 + wr * 5 + kw];
                        acc[o][0][0] = fmaf(row[kw], wv, acc[o][0][0]);
                        acc[o][0][1] = fmaf(row[kw + 2], wv, acc[o][0][1]);
                    }
                    if (wr >= 2) {  // di=1, kh=wr-2
                        float wv = w[o * 75 + c * 25 + (wr - 2) * 5 + kw];
                        acc[o][1][0] = fmaf(row[kw], wv, acc[o][1][0]);
                        acc[o][1][1] = fmaf(row[kw + 2], wv, acc[o][1][1]);
                    }
                }
            }
        }
    }
    __syncthreads();  // all stage reads done -> safe to alias

    // relu + stash conv tile [6][32][33]
    #pragma unroll
    for (int o = 0; o < 6; ++o)
        #pragma unroll
        for (int di = 0; di < 2; ++di)
            #pragma unroll
            for (int dj = 0; dj < 2; ++dj)
                sbuf[(o * 32 + 2 * i + di) * 33 + (2 * j + dj)] =
                    fmaxf(acc[o][di][dj], 0.0f);
    __syncthreads();

    // pool 2x2 s1 -> 31x31, write global
    for (int l = tid; l < 6 * 31 * 31; l += 256) {
        int o = l / 961;
        int rem = l - o * 961;
        int pi = rem / 31;
        int pj = rem - pi * 31;
        int gr = pr0 + pi, gc = pc0 + pj;
        if (gr < 123 && gc < 123) {
            const float* p = &sbuf[(o * 32 + pi) * 33 + pj];
            float m = fmaxf(fmaxf(p[0], p[1]), fmaxf(p[33], p[34]));
            out[((size_t)(b * 6 + o) * 123 + gr) * 123 + gc] = m;
        }
    }
}

// ============ conv2 + relu + pool2 fused (unchanged) ============
__global__ __launch_bounds__(256) void conv2f_k(const float* __restrict__ in,
                                                const float* __restrict__ w,
                                                const float* __restrict__ bias,
                                                float* __restrict__ out) {
    __shared__ float sbuf[6 * 33 * 33];
    const int tc = blockIdx.x, tr = blockIdx.y, b = blockIdx.z;
    const int pr0 = tr * 15, pc0 = tc * 15;
    const int tid = threadIdx.x;

    const float* inb = in + (size_t)b * 6 * 123 * 123;
    const int ir0 = 2 * pr0 - 1, ic0 = 2 * pc0 - 1;
    for (int l = tid; l < 6 * 33 * 33; l += 256) {
        int c = l / (33 * 33);
        int rem = l - c * (33 * 33);
        int y = rem / 33;
        int x = rem - y * 33;
        int gr = ir0 + y, gc = ic0 + x;
        float v = 0.0f;
        if (gr >= 0 && gr < 123 && gc >= 0 && gc < 123)
            v = inb[((size_t)c * 123 + gr) * 123 + gc];
        sbuf[l] = v;
    }
    __syncthreads();

    const int ti = tid >> 4, tj = tid & 15;
    float acc[15];
    #pragma unroll
    for (int o = 0; o < 15; ++o) acc[o] = bias[o];
    for (int c = 0; c < 6; ++c) {
        #pragma unroll
        for (int kh = 0; kh < 3; ++kh) {
            const float* r = &sbuf[(c * 33 + 2 * ti + kh) * 33 + 2 * tj];
            float a0 = r[0], a1 = r[1], a2 = r[2];
            #pragma unroll
            for (int o = 0; o < 15; ++o) {
                const float* wr = &w[o * 54 + c * 9 + kh * 3];
                acc[o] = fmaf(a0, wr[0], acc[o]);
                acc[o] = fmaf(a1, wr[1], acc[o]);
                acc[o] = fmaf(a2, wr[2], acc[o]);
            }
        }
    }
    __syncthreads();

    float* cv = sbuf;  // [15][16][17]
    #pragma unroll
    for (int o = 0; o < 15; ++o)
        cv[(o * 16 + ti) * 17 + tj] = fmaxf(acc[o], 0.0f);
    __syncthreads();

    for (int l = tid; l < 15 * 15 * 15; l += 256) {
        int o = l / 225;
        int rem = l - o * 225;
        int pi = rem / 15;
        int pj = rem - pi * 15;
        int gr = pr0 + pi, gc = pc0 + pj;
        if (gr < 61 && gc < 61) {
            const float* p = &cv[(o * 16 + pi) * 17 + pj];
            float m = fmaxf(fmaxf(p[0], p[1]), fmaxf(p[17], p[18]));
            out[((size_t)(b * 15 + o) * 61 + gr) * 61 + gc] = m;
        }
    }
}

// ---------------- fc1 v2: split-K x MN-quadrant GEMM.
// grid (SPLITK, 4): s = K-split; mh = y>>1 (64-row half), nh = y&1 (60-col half).
// Partials P[s][128][120], each block writes its disjoint 64x60 quadrant.
__global__ __launch_bounds__(256) void fc1_k(const float* __restrict__ X,
                                             const float* __restrict__ W,
                                             float* __restrict__ P) {
    __shared__ float Xs[16][68];
    __shared__ float Ws[16][68];
    const int K = FC1_K;
    const int chunk = (K + SPLITK - 1) / SPLITK;  // 219
    const int s = blockIdx.x;
    const int mh = blockIdx.y >> 1, nh = blockIdx.y & 1;
    const int m0 = mh * 64, n0 = nh * 60;
    int ks = s * chunk;
    int ke = min(ks + chunk, K);
    int tid = threadIdx.x;
    int tx = tid & 15, ty = tid >> 4;
    float acc[4][4];
    #pragma unroll
    for (int ii = 0; ii < 4; ++ii)
        #pragma unroll
        for (int jj = 0; jj < 4; ++jj) acc[ii][jj] = 0.0f;

    for (int k0 = ks; k0 < ke; k0 += 16) {
        int krem = ke - k0;
        __syncthreads();
        #pragma unroll
        for (int it = 0; it < 4; ++it) {
            int l = it * 256 + tid;
            int kk = l & 15, r = l >> 4;  // r: 0..63
            bool kv = kk < krem;
            Xs[kk][r] = kv ? X[(size_t)(m0 + r) * K + k0 + kk] : 0.0f;
            Ws[kk][r] = (kv && r < 60) ? W[(size_t)(n0 + r) * K + k0 + kk] : 0.0f;
        }
        __syncthreads();
        #pragma unroll
        for (int kk = 0; kk < 16; ++kk) {
            float4 a = *(const float4*)&Xs[kk][ty * 4];
            float4 bb = *(const float4*)&Ws[kk][tx * 4];
            float av[4] = {a.x, a.y, a.z, a.w};
            float bv[4] = {bb.x, bb.y, bb.z, bb.w};
            #pragma unroll
            for (int ii = 0; ii < 4; ++ii)
                #pragma unroll
                for (int jj = 0; jj < 4; ++jj)
                    acc[ii][jj] = fmaf(av[ii], bv[jj], acc[ii][jj]);
        }
    }
    float* Pp = P + (size_t)s * 15360;
    #pragma unroll
    for (int ii = 0; ii < 4; ++ii) {
        int m = m0 + ty * 4 + ii;
        #pragma unroll
        for (int jj = 0; jj < 4; ++jj) {
            int nn = tx * 4 + jj;
            if (nn < 60) Pp[m * 120 + n0 + nn] = acc[ii][jj];
        }
    }
}

// ---------------- tail: reduce partials, fc1 bias+relu, fc2, fc3, quantum head
__global__ __launch_bounds__(128) void tail_k(const float* __restrict__ P,
                                              const float* __restrict__ f1b,
                                              const float* __restrict__ f2w,
                                              const float* __restrict__ f2b,
                                              const float* __restrict__ f3w,
                                              const float* __restrict__ f3b,
                                              const float* __restrict__ qp,
                                              float* __restrict__ out) {
    __shared__ float x1[120];
    __shared__ float x2[84];
    int b = blockIdx.x, tid = threadIdx.x;
    if (tid < 120) {
        float acc = f1b[tid];
        const float* p = P + (size_t)b * 120 + tid;
        for (int s = 0; s < SPLITK; ++s) acc += p[(size_t)s * 15360];
        x1[tid] = fmaxf(acc, 0.0f);
    }
    __syncthreads();
    if (tid < 84) {
        float acc = f2b[tid];
        const float* wr = f2w + tid * 120;
        #pragma unroll 4
        for (int n = 0; n < 120; ++n) acc = fmaf(x1[n], wr[n], acc);
        x2[tid] = fmaxf(acc, 0.0f);
    }
    __syncthreads();
    if (tid == 0) {
        float x = f3b[0];
        for (int m = 0; m < 84; ++m) x = fmaf(x2[m], f3w[m], x);
        float sr[16], si[16];
        #pragma unroll
        for (int i = 0; i < 16; ++i) { sr[i] = 0.0f; si[i] = 0.0f; }
        sr[0] = 1.0f;
        float c0 = cosf(0.5f * x), s0 = sinf(0.5f * x);
        #pragma unroll
        for (int w = 0; w < 4; ++w) {
            int mask = 8 >> w;
            #pragma unroll
            for (int idx = 0; idx < 16; ++idx) {
                if (idx & mask) continue;
                int i1 = idx | mask;
                float a0r = sr[idx], a0i = si[idx], a1r = sr[i1], a1i = si[i1];
                sr[idx] = c0 * a0r - s0 * a1r;  si[idx] = c0 * a0i - s0 * a1i;
                sr[i1]  = s0 * a0r + c0 * a1r;  si[i1]  = s0 * a0i + c0 * a1i;
            }
        }
        for (int layer = 0; layer < 2; ++layer) {
            #pragma unroll
            for (int w = 0; w < 4; ++w) {
                int gi = (layer * 4 + w) * 3;
                float phi = qp[gi], th = qp[gi + 1], om = qp[gi + 2];
                float hs = 0.5f * (phi + om), hd = 0.5f * (phi - om);
                float ct = cosf(0.5f * th), st = sinf(0.5f * th);
                float chs = cosf(hs), shs = sinf(hs);
                float chd = cosf(hd), shd = sinf(hd);
                float m00r = chs * ct,  m00i = -shs * ct;
                float m01r = -chd * st, m01i = -shd * st;
                float m10r = chd * st,  m10i = -shd * st;
                float m11r = chs * ct,  m11i = shs * ct;
                int mask = 8 >> w;
                #pragma unroll
                for (int idx = 0; idx < 16; ++idx) {
                    if (idx & mask) continue;
                    int i1 = idx | mask;
                    float a0r = sr[idx], a0i = si[idx], a1r = sr[i1], a1i = si[i1];
                    sr[idx] = m00r * a0r - m00i * a0i + m01r * a1r - m01i * a1i;
                    si[idx] = m00r * a0i + m00i * a0r + m01r * a1i + m01i * a1r;
                    sr[i1]  = m10r * a0r - m10i * a0i + m11r * a1r - m11i * a1i;
                    si[i1]  = m10r * a0i + m10i * a0r + m11r * a1i + m11i * a1r;
                }
            }
            #pragma unroll
            for (int cw = 0; cw < 3; ++cw) {
                int cm = 8 >> cw, tm = 8 >> (cw + 1);
                #pragma unroll
                for (int idx = 0; idx < 16; ++idx) {
                    if ((idx & cm) && !(idx & tm)) {
                        int i1 = idx | tm;
                        float tr = sr[idx]; sr[idx] = sr[i1]; sr[i1] = tr;
                        float ti = si[idx]; si[idx] = si[i1]; si[i1] = ti;
                    }
                }
            }
        }
        float q = 0.0f;
        #pragma unroll
        for (int idx = 0; idx < 16; ++idx) {
            float p2 = sr[idx] * sr[idx] + si[idx] * si[idx];
            q += (idx < 8) ? p2 : -p2;
        }
        float pr = 0.5f * (q + 1.0f);
        out[2 * b] = pr;
        out[2 * b + 1] = 1.0f - pr;
    }
}

extern "C" void kernel_launch(void* const* d_in, const int* in_sizes, int n_in,
                              void* d_out, int out_size, void* d_ws, size_t ws_size,
                              hipStream_t stream) {
    const float* inp = (const float*)d_in[0];
    const float* c1w = (const float*)d_in[1];
    const float* c1b = (const float*)d_in[2];
    const float* c2w = (const float*)d_in[3];
    const float* c2b = (const float*)d_in[4];
    const float* f1w = (const float*)d_in[5];
    const float* f1b = (const float*)d_in[6];
    const float* f2w = (const float*)d_in[7];
    const float* f2b = (const float*)d_in[8];
    const float* f3w = (const float*)d_in[9];
    const float* f3b = (const float*)d_in[10];
    const float* qp  = (const float*)d_in[11];
    float* out = (float*)d_out;
    float* ws = (float*)d_ws;

    // ws layout (floats):
    //   B (pool1 out) @ 0          : 128*6*123*123  = 11,619,072
    //   D (pool2 out) @ 11,619,072 : 128*15*61*61   =  7,144,320
    //   P (fc1 part.) @ 18,763,392 : SPLITK*128*120 =  3,932,160   (total 90.8 MB)
    float* B = ws;
    float* D = ws + 11619072;
    float* P = ws + 18763392;

    conv1f_k<<<dim3(4, 4, 128), 256, 0, stream>>>(inp, c1w, c1b, B);
    conv2f_k<<<dim3(5, 5, 128), 256, 0, stream>>>(B, c2w, c2b, D);
    fc1_k<<<dim3(SPLITK, 4), 256, 0, stream>>>(D, f1w, P);
    tail_k<<<128, 128, 0, stream>>>(P, f1b, f2w, f2b, f3w, f3b, qp, out);
}

// Round 7
// 186.958 us; speedup vs baseline: 4.3161x; 1.1459x over previous
//
#include <hip/hip_runtime.h>

#define SPLITK 256
#define FC1_K 55815

// ============ conv1 + relu + pool1 fused (v3: per-channel double-buffered pipeline) ============
// in (128,3,250,250) --5x5 s2 p1--> conv (128,6,124,124) --relu--2x2 s1 pool--> out (128,6,123,123)
// Block: 31x31 pooled tile (conv 32x32, input window 67x67, staged stride-68).
// Pipeline: load c+1 -> regs; compute c from LDS; write regs -> LDS; 1 sync/channel.
__global__ __launch_bounds__(256) void conv1f_k(const float* __restrict__ in,
                                                const float* __restrict__ w,
                                                const float* __restrict__ bias,
                                                float* __restrict__ out) {
    __shared__ float sb[2][4608];  // 36 KB; stash alias (6336 floats) spans both
    const int tc = blockIdx.x, tr = blockIdx.y, b = blockIdx.z;
    const int pr0 = tr * 31, pc0 = tc * 31;
    const int tid = threadIdx.x;
    const int i = tid >> 4, j = tid & 15;
    const float* inb = in + (size_t)b * 187500;
    const int ir0 = 2 * pr0 - 1, ic0 = 2 * pc0 - 1;

    float acc[6][2][2];
    #pragma unroll
    for (int o = 0; o < 6; ++o) {
        float bv = bias[o];
        acc[o][0][0] = bv; acc[o][0][1] = bv; acc[o][1][0] = bv; acc[o][1][1] = bv;
    }

    float stg[18];
    // load channel c's 67x67 window (stride-68 layout, 4608-padded) into regs
    auto load_ch = [&](int c) {
        const float* cp = inb + c * 62500;
        int y = tid / 68;
        int x = tid - y * 68;
        #pragma unroll
        for (int it = 0; it < 18; ++it) {
            int gr = ir0 + y, gc = ic0 + x;
            float v = 0.0f;
            if ((unsigned)gr < 250u && (unsigned)gc < 250u)
                v = cp[gr * 250 + gc];
            stg[it] = v;
            x += 52; y += 3;                 // l += 256 == 3*68 + 52
            if (x >= 68) { x -= 68; ++y; }
        }
    };
    auto write_ch = [&](float* dst) {
        #pragma unroll
        for (int it = 0; it < 18; ++it) dst[tid + it * 256] = stg[it];
    };
    auto compute_ch = [&](int c, const float* src) {
        #pragma unroll
        for (int wr = 0; wr < 7; ++wr) {
            const float* rp = &src[(4 * i + wr) * 68 + 4 * j];
            float row[7];
            float4 v4 = *(const float4*)rp;
            float2 v2 = *(const float2*)(rp + 4);
            row[0] = v4.x; row[1] = v4.y; row[2] = v4.z; row[3] = v4.w;
            row[4] = v2.x; row[5] = v2.y; row[6] = rp[6];
            #pragma unroll
            for (int o = 0; o < 6; ++o) {
                #pragma unroll
                for (int kw = 0; kw < 5; ++kw) {
                    if (wr <= 4) {
                        float wv = w[o * 75 + c * 25 + wr * 5 + kw];
                        acc[o][0][0] = fmaf(row[kw], wv, acc[o][0][0]);
                        acc[o][0][1] = fmaf(row[kw + 2], wv, acc[o][0][1]);
                    }
                    if (wr >= 2) {
                        float wv = w[o * 75 + c * 25 + (wr - 2) * 5 + kw];
                        acc[o][1][0] = fmaf(row[kw], wv, acc[o][1][0]);
                        acc[o][1][1] = fmaf(row[kw + 2], wv, acc[o][1][1]);
                    }
                }
            }
        }
    };

    load_ch(0); write_ch(sb[0]);
    __syncthreads();
    load_ch(1); compute_ch(0, sb[0]); write_ch(sb[1]);
    __syncthreads();
    load_ch(2); compute_ch(1, sb[1]); write_ch(sb[0]);  // buf0 readers done at prev sync
    __syncthreads();
    compute_ch(2, sb[0]);
    __syncthreads();  // all stage reads done -> safe to alias stash over sb

    // relu + stash conv tile [6][32][33]
    float* cv = &sb[0][0];
    #pragma unroll
    for (int o = 0; o < 6; ++o)
        #pragma unroll
        for (int di = 0; di < 2; ++di)
            #pragma unroll
            for (int dj = 0; dj < 2; ++dj)
                cv[(o * 32 + 2 * i + di) * 33 + (2 * j + dj)] = fmaxf(acc[o][di][dj], 0.0f);
    __syncthreads();

    // pool 2x2 s1: thread owns pool quad (2i..2i+1, 2j..2j+1); reads its 3x3 conv window
    const int gr0 = pr0 + 2 * i, gc0 = pc0 + 2 * j;
    const bool r1in = (2 * i + 1 < 31) && (gr0 + 1 < 123);
    const bool c1in = (2 * j + 1 < 31) && (gc0 + 1 < 123);
    const bool r0in = gr0 < 123, c0in = gc0 < 123;  // 2i,2j always < 31
    #pragma unroll
    for (int o = 0; o < 6; ++o) {
        const float* p0 = &cv[(o * 32 + 2 * i) * 33 + 2 * j];
        float c00 = p0[0], c01 = p0[1], c02 = p0[2];
        float c10 = p0[33], c11 = p0[34], c12 = p0[35];
        float c20 = p0[66], c21 = p0[67], c22 = p0[68];  // row 2i+2: mem-safe (<9216)
        float* orow = out + ((size_t)(b * 6 + o) * 123 + gr0) * 123 + gc0;
        if (r0in && c0in) orow[0]   = fmaxf(fmaxf(c00, c01), fmaxf(c10, c11));
        if (r0in && c1in) orow[1]   = fmaxf(fmaxf(c01, c02), fmaxf(c11, c12));
        if (r1in && c0in) orow[123] = fmaxf(fmaxf(c10, c11), fmaxf(c20, c21));
        if (r1in && c1in) orow[124] = fmaxf(fmaxf(c11, c12), fmaxf(c21, c22));
    }
}

// ============ conv2 + relu + pool2 fused (v3: per-channel double-buffered pipeline) ============
// in (128,6,123,123) --3x3 s2 p1--> conv (128,15,62,62) --relu--pool--> out (128,15,61,61)
// Block: 15x15 pooled tile (conv 16x16, input window 33x33, staged stride-34).
__global__ __launch_bounds__(256) void conv2f_k(const float* __restrict__ in,
                                                const float* __restrict__ w,
                                                const float* __restrict__ bias,
                                                float* __restrict__ out) {
    __shared__ float smem[4080];  // stage: buf0 @0, buf1 @1280 (1280 each); stash [15][16][17]=4080 aliases
    const int tc = blockIdx.x, tr = blockIdx.y, b = blockIdx.z;
    const int pr0 = tr * 15, pc0 = tc * 15;
    const int tid = threadIdx.x;
    const int ti = tid >> 4, tj = tid & 15;
    const float* inb = in + (size_t)b * 6 * 15129;
    const int ir0 = 2 * pr0 - 1, ic0 = 2 * pc0 - 1;

    float acc[15];
    #pragma unroll
    for (int o = 0; o < 15; ++o) acc[o] = bias[o];

    float stg[5];
    auto load_ch = [&](int c) {
        const float* cp = inb + c * 15129;
        int y = tid / 34;
        int x = tid - y * 34;
        #pragma unroll
        for (int it = 0; it < 5; ++it) {
            int gr = ir0 + y, gc = ic0 + x;
            float v = 0.0f;
            if ((unsigned)gr < 123u && (unsigned)gc < 123u)
                v = cp[gr * 123 + gc];
            stg[it] = v;
            x += 18; y += 7;                 // l += 256 == 7*34 + 18
            if (x >= 34) { x -= 34; ++y; }
        }
    };
    auto write_ch = [&](float* dst) {
        #pragma unroll
        for (int it = 0; it < 5; ++it) dst[tid + it * 256] = stg[it];
    };
    auto compute_ch = [&](int c, const float* src) {
        #pragma unroll
        for (int kh = 0; kh < 3; ++kh) {
            const float* r = &src[(2 * ti + kh) * 34 + 2 * tj];
            float a0 = r[0], a1 = r[1], a2 = r[2];
            #pragma unroll
            for (int o = 0; o < 15; ++o) {
                const float* wr_ = &w[o * 54 + c * 9 + kh * 3];
                acc[o] = fmaf(a0, wr_[0], acc[o]);
                acc[o] = fmaf(a1, wr_[1], acc[o]);
                acc[o] = fmaf(a2, wr_[2], acc[o]);
            }
        }
    };

    float* b0 = smem, *b1 = smem + 1280;
    load_ch(0); write_ch(b0);
    __syncthreads();
    load_ch(1); compute_ch(0, b0); write_ch(b1);
    __syncthreads();
    load_ch(2); compute_ch(1, b1); write_ch(b0);
    __syncthreads();
    load_ch(3); compute_ch(2, b0); write_ch(b1);
    __syncthreads();
    load_ch(4); compute_ch(3, b1); write_ch(b0);
    __syncthreads();
    load_ch(5); compute_ch(4, b0); write_ch(b1);
    __syncthreads();
    compute_ch(5, b1);
    __syncthreads();  // before stash alias overwrite

    // relu + stash conv tile [15][16][17]
    #pragma unroll
    for (int o = 0; o < 15; ++o)
        smem[(o * 16 + ti) * 17 + tj] = fmaxf(acc[o], 0.0f);
    __syncthreads();

    // pool: thread owns pool pos (ti,tj) if ti<15 && tj<15
    const int gr = pr0 + ti, gc = pc0 + tj;
    if (ti < 15 && tj < 15 && gr < 61 && gc < 61) {
        #pragma unroll
        for (int o = 0; o < 15; ++o) {
            const float* p = &smem[(o * 16 + ti) * 17 + tj];
            float m = fmaxf(fmaxf(p[0], p[1]), fmaxf(p[17], p[18]));
            out[((size_t)(b * 15 + o) * 61 + gr) * 61 + gc] = m;
        }
    }
}

// ---------------- fc1 v2: split-K x MN-quadrant GEMM.
// grid (SPLITK, 4): s = K-split; mh = y>>1 (64-row half), nh = y&1 (60-col half).
__global__ __launch_bounds__(256) void fc1_k(const float* __restrict__ X,
                                             const float* __restrict__ W,
                                             float* __restrict__ P) {
    __shared__ float Xs[16][68];
    __shared__ float Ws[16][68];
    const int K = FC1_K;
    const int chunk = (K + SPLITK - 1) / SPLITK;  // 219
    const int s = blockIdx.x;
    const int mh = blockIdx.y >> 1, nh = blockIdx.y & 1;
    const int m0 = mh * 64, n0 = nh * 60;
    int ks = s * chunk;
    int ke = min(ks + chunk, K);
    int tid = threadIdx.x;
    int tx = tid & 15, ty = tid >> 4;
    float acc[4][4];
    #pragma unroll
    for (int ii = 0; ii < 4; ++ii)
        #pragma unroll
        for (int jj = 0; jj < 4; ++jj) acc[ii][jj] = 0.0f;

    for (int k0 = ks; k0 < ke; k0 += 16) {
        int krem = ke - k0;
        __syncthreads();
        #pragma unroll
        for (int it = 0; it < 4; ++it) {
            int l = it * 256 + tid;
            int kk = l & 15, r = l >> 4;
            bool kv = kk < krem;
            Xs[kk][r] = kv ? X[(size_t)(m0 + r) * K + k0 + kk] : 0.0f;
            Ws[kk][r] = (kv && r < 60) ? W[(size_t)(n0 + r) * K + k0 + kk] : 0.0f;
        }
        __syncthreads();
        #pragma unroll
        for (int kk = 0; kk < 16; ++kk) {
            float4 a = *(const float4*)&Xs[kk][ty * 4];
            float4 bb = *(const float4*)&Ws[kk][tx * 4];
            float av[4] = {a.x, a.y, a.z, a.w};
            float bv[4] = {bb.x, bb.y, bb.z, bb.w};
            #pragma unroll
            for (int ii = 0; ii < 4; ++ii)
                #pragma unroll
                for (int jj = 0; jj < 4; ++jj)
                    acc[ii][jj] = fmaf(av[ii], bv[jj], acc[ii][jj]);
        }
    }
    float* Pp = P + (size_t)s * 15360;
    #pragma unroll
    for (int ii = 0; ii < 4; ++ii) {
        int m = m0 + ty * 4 + ii;
        #pragma unroll
        for (int jj = 0; jj < 4; ++jj) {
            int nn = tx * 4 + jj;
            if (nn < 60) Pp[m * 120 + n0 + nn] = acc[ii][jj];
        }
    }
}

// ---------------- tail: reduce partials, fc1 bias+relu, fc2, fc3, quantum head
__global__ __launch_bounds__(128) void tail_k(const float* __restrict__ P,
                                              const float* __restrict__ f1b,
                                              const float* __restrict__ f2w,
                                              const float* __restrict__ f2b,
                                              const float* __restrict__ f3w,
                                              const float* __restrict__ f3b,
                                              const float* __restrict__ qp,
                                              float* __restrict__ out) {
    __shared__ float x1[120];
    __shared__ float x2[84];
    int b = blockIdx.x, tid = threadIdx.x;
    if (tid < 120) {
        float acc = f1b[tid];
        const float* p = P + (size_t)b * 120 + tid;
        for (int s = 0; s < SPLITK; ++s) acc += p[(size_t)s * 15360];
        x1[tid] = fmaxf(acc, 0.0f);
    }
    __syncthreads();
    if (tid < 84) {
        float acc = f2b[tid];
        const float* wr = f2w + tid * 120;
        #pragma unroll 4
        for (int n = 0; n < 120; ++n) acc = fmaf(x1[n], wr[n], acc);
        x2[tid] = fmaxf(acc, 0.0f);
    }
    __syncthreads();
    if (tid == 0) {
        float x = f3b[0];
        for (int m = 0; m < 84; ++m) x = fmaf(x2[m], f3w[m], x);
        float sr[16], si[16];
        #pragma unroll
        for (int i = 0; i < 16; ++i) { sr[i] = 0.0f; si[i] = 0.0f; }
        sr[0] = 1.0f;
        float c0 = cosf(0.5f * x), s0 = sinf(0.5f * x);
        #pragma unroll
        for (int w = 0; w < 4; ++w) {
            int mask = 8 >> w;
            #pragma unroll
            for (int idx = 0; idx < 16; ++idx) {
                if (idx & mask) continue;
                int i1 = idx | mask;
                float a0r = sr[idx], a0i = si[idx], a1r = sr[i1], a1i = si[i1];
                sr[idx] = c0 * a0r - s0 * a1r;  si[idx] = c0 * a0i - s0 * a1i;
                sr[i1]  = s0 * a0r + c0 * a1r;  si[i1]  = s0 * a0i + c0 * a1i;
            }
        }
        for (int layer = 0; layer < 2; ++layer) {
            #pragma unroll
            for (int w = 0; w < 4; ++w) {
                int gi = (layer * 4 + w) * 3;
                float phi = qp[gi], th = qp[gi + 1], om = qp[gi + 2];
                float hs = 0.5f * (phi + om), hd = 0.5f * (phi - om);
                float ct = cosf(0.5f * th), st = sinf(0.5f * th);
                float chs = cosf(hs), shs = sinf(hs);
                float chd = cosf(hd), shd = sinf(hd);
                float m00r = chs * ct,  m00i = -shs * ct;
                float m01r = -chd * st, m01i = -shd * st;
                float m10r = chd * st,  m10i = -shd * st;
                float m11r = chs * ct,  m11i = shs * ct;
                int mask = 8 >> w;
                #pragma unroll
                for (int idx = 0; idx < 16; ++idx) {
                    if (idx & mask) continue;
                    int i1 = idx | mask;
                    float a0r = sr[idx], a0i = si[idx], a1r = sr[i1], a1i = si[i1];
                    sr[idx] = m00r * a0r - m00i * a0i + m01r * a1r - m01i * a1i;
                    si[idx] = m00r * a0i + m00i * a0r + m01r * a1i + m01i * a1r;
                    sr[i1]  = m10r * a0r - m10i * a0i + m11r * a1r - m11i * a1i;
                    si[i1]  = m10r * a0i + m10i * a0r + m11r * a1i + m11i * a1r;
                }
            }
            #pragma unroll
            for (int cw = 0; cw < 3; ++cw) {
                int cm = 8 >> cw, tm = 8 >> (cw + 1);
                #pragma unroll
                for (int idx = 0; idx < 16; ++idx) {
                    if ((idx & cm) && !(idx & tm)) {
                        int i1 = idx | tm;
                        float tr = sr[idx]; sr[idx] = sr[i1]; sr[i1] = tr;
                        float ti = si[idx]; si[idx] = si[i1]; si[i1] = ti;
                    }
                }
            }
        }
        float q = 0.0f;
        #pragma unroll
        for (int idx = 0; idx < 16; ++idx) {
            float p2 = sr[idx] * sr[idx] + si[idx] * si[idx];
            q += (idx < 8) ? p2 : -p2;
        }
        float pr = 0.5f * (q + 1.0f);
        out[2 * b] = pr;
        out[2 * b + 1] = 1.0f - pr;
    }
}

extern "C" void kernel_launch(void* const* d_in, const int* in_sizes, int n_in,
                              void* d_out, int out_size, void* d_ws, size_t ws_size,
                              hipStream_t stream) {
    const float* inp = (const float*)d_in[0];
    const float* c1w = (const float*)d_in[1];
    const float* c1b = (const float*)d_in[2];
    const float* c2w = (const float*)d_in[3];
    const float* c2b = (const float*)d_in[4];
    const float* f1w = (const float*)d_in[5];
    const float* f1b = (const float*)d_in[6];
    const float* f2w = (const float*)d_in[7];
    const float* f2b = (const float*)d_in[8];
    const float* f3w = (const float*)d_in[9];
    const float* f3b = (const float*)d_in[10];
    const float* qp  = (const float*)d_in[11];
    float* out = (float*)d_out;
    float* ws = (float*)d_ws;

    // ws layout (floats):
    //   B (pool1 out) @ 0          : 128*6*123*123  = 11,619,072
    //   D (pool2 out) @ 11,619,072 : 128*15*61*61   =  7,144,320
    //   P (fc1 part.) @ 18,763,392 : SPLITK*128*120 =  3,932,160   (total 90.8 MB)
    float* B = ws;
    float* D = ws + 11619072;
    float* P = ws + 18763392;

    conv1f_k<<<dim3(4, 4, 128), 256, 0, stream>>>(inp, c1w, c1b, B);
    conv2f_k<<<dim3(5, 5, 128), 256, 0, stream>>>(B, c2w, c2b, D);
    fc1_k<<<dim3(SPLITK, 4), 256, 0, stream>>>(D, f1w, P);
    tail_k<<<128, 128, 0, stream>>>(P, f1b, f2w, f2b, f3w, f3b, qp, out);
}